// Round 7
// baseline (368.092 us; speedup 1.0000x reference)
//
#include <hip/hip_runtime.h>

constexpr int NNODES = 100000;
constexpr int NEDGES = 1600000;
constexpr int K = 128;
constexpr int NB1 = (NNODES + 255) / 256;   // 391 scan blocks
constexpr int NSLICE = 8;
constexpr int NODES_PER_SLICE = NNODES / NSLICE;   // 12500
constexpr int EPB_A = NEDGES / 256;                // 6250 edges per phase-A block
constexpr int SCAP = 262144;                       // staged capacity per slice (~200K expected)

typedef __attribute__((ext_vector_type(8))) short bf16x8;
typedef __attribute__((ext_vector_type(4))) float f32x4;

__device__ __forceinline__ unsigned short f2bf(float f) {   // RTNE
    unsigned u = __float_as_uint(f);
    unsigned r = (u + 0x7fffu + ((u >> 16) & 1u)) >> 16;
    return (unsigned short)r;
}
__device__ __forceinline__ void acc2(float& a0, float& a1, unsigned u) {
    a0 += __uint_as_float(u << 16);
    a1 += __uint_as_float(u & 0xffff0000u);
}
__device__ __forceinline__ void acc8(float* a, uint4 v) {
    acc2(a[0], a[1], v.x); acc2(a[2], a[3], v.y);
    acc2(a[4], a[5], v.z); acc2(a[6], a[7], v.w);
}

__global__ void zero_int_kernel(int* __restrict__ p, int n) {
    int i = blockIdx.x * 256 + threadIdx.x;
    if (i < n) p[i] = 0;
}

// x (fp32) -> bf16, 8 elems/thread
__global__ void xcast_kernel(const float4* __restrict__ in, uint4* __restrict__ out, int n8) {
    int i = blockIdx.x * 256 + threadIdx.x;
    if (i >= n8) return;
    float4 a = in[2 * i], b = in[2 * i + 1];
    uint4 w;
    w.x = (unsigned)f2bf(a.x) | ((unsigned)f2bf(a.y) << 16);
    w.y = (unsigned)f2bf(a.z) | ((unsigned)f2bf(a.w) << 16);
    w.z = (unsigned)f2bf(b.x) | ((unsigned)f2bf(b.y) << 16);
    w.w = (unsigned)f2bf(b.z) | ((unsigned)f2bf(b.w) << 16);
    out[i] = w;
}

// cast + transpose weights to bf16 [N][K]; Wt2 = concat([W2l|W2r] cols)
__global__ void wprep_kernel(const float* __restrict__ W1l, const float* __restrict__ W1r,
                             const float* __restrict__ W2l, const float* __restrict__ W2r,
                             unsigned short* __restrict__ Wt1l, unsigned short* __restrict__ Wt1r,
                             unsigned short* __restrict__ Wt2) {
    int idx = blockIdx.x * 256 + threadIdx.x;     // [n][k], n-major
    if (idx >= 128 * 128) return;
    int n = idx >> 7, k = idx & 127;
    Wt1l[idx] = f2bf(W1l[k * 128 + n]);
    Wt1r[idx] = f2bf(W1r[k * 128 + n]);
    Wt2[idx]  = f2bf(n < 64 ? W2l[k * 64 + n] : W2r[k * 64 + (n - 64)]);
}

// Phase A: bin edges by dst-slice into staged SoA buckets. One read of src/dst.
__global__ void binA_kernel(const int* __restrict__ src, const int* __restrict__ dst,
                            int* __restrict__ slice_alloc,
                            int* __restrict__ stagedD, int* __restrict__ stagedS) {
    __shared__ int cnt[NSLICE];
    __shared__ int base[NSLICE];
    int tid = threadIdx.x;
    if (tid < NSLICE) cnt[tid] = 0;
    __syncthreads();
    int e0 = blockIdx.x * EPB_A;
    // pass 1: count per slice
    for (int e = e0 + tid; e < e0 + EPB_A; e += 256)
        atomicAdd(&cnt[dst[e] / NODES_PER_SLICE], 1);
    __syncthreads();
    if (tid < NSLICE) {
        base[tid] = atomicAdd(&slice_alloc[tid], cnt[tid]);
        cnt[tid] = 0;                       // becomes intra-block cursor
    }
    __syncthreads();
    // pass 2: place (dst reads are L2-warm)
    for (int e = e0 + tid; e < e0 + EPB_A; e += 256) {
        int d = dst[e];
        int sl = d / NODES_PER_SLICE;
        int pos = base[sl] + atomicAdd(&cnt[sl], 1);
        if (pos < SCAP) {                   // impossible overflow guard (>100 sigma)
            stagedD[sl * SCAP + pos] = d;
            stagedS[sl * SCAP + pos] = src[e];
        }
    }
}

// Phase B1: per-slice histogram (deg slice is XCD-L2-resident)
__global__ void binB1_kernel(const int* __restrict__ slice_alloc,
                             const int* __restrict__ stagedD, int* __restrict__ deg) {
    int sl = blockIdx.x & 7, sub = blockIdx.x >> 3;
    int n = min(slice_alloc[sl], SCAP);
    const int* sd = stagedD + sl * SCAP;
    for (int i = sub * 256 + threadIdx.x; i < n; i += 65536)
        atomicAdd(&deg[sd[i]], 1);
}

// Phase B2: per-slice place into csr (cursor + csr region XCD-L2-resident)
__global__ void binB2_kernel(const int* __restrict__ slice_alloc,
                             const int* __restrict__ stagedD, const int* __restrict__ stagedS,
                             int* __restrict__ cursor, int* __restrict__ csr_src) {
    int sl = blockIdx.x & 7, sub = blockIdx.x >> 3;
    int n = min(slice_alloc[sl], SCAP);
    const int* sd = stagedD + sl * SCAP;
    const int* ss = stagedS + sl * SCAP;
    for (int i = sub * 256 + threadIdx.x; i < n; i += 65536) {
        int pos = atomicAdd(&cursor[sd[i]], 1);
        csr_src[pos] = ss[i];
    }
}

__global__ void scan1_kernel(const int* __restrict__ deg, int* __restrict__ row_start,
                             int* __restrict__ blocksum) {
    __shared__ int tmp[256];
    int i = blockIdx.x * 256 + threadIdx.x;
    int v = (i < NNODES) ? deg[i] : 0;
    tmp[threadIdx.x] = v;
    __syncthreads();
    #pragma unroll
    for (int off = 1; off < 256; off <<= 1) {
        int t = (threadIdx.x >= off) ? tmp[threadIdx.x - off] : 0;
        __syncthreads();
        tmp[threadIdx.x] += t;
        __syncthreads();
    }
    if (i < NNODES) row_start[i] = tmp[threadIdx.x] - v;   // exclusive
    if (threadIdx.x == 255) blocksum[blockIdx.x] = tmp[255];
}

__global__ void scan2_kernel(int* __restrict__ blocksum, int* __restrict__ blockoff) {
    __shared__ int tmp[512];
    int t = threadIdx.x;
    int v = (t < NB1) ? blocksum[t] : 0;
    tmp[t] = v;
    __syncthreads();
    #pragma unroll
    for (int off = 1; off < 512; off <<= 1) {
        int u = (t >= off) ? tmp[t - off] : 0;
        __syncthreads();
        tmp[t] += u;
        __syncthreads();
    }
    if (t < NB1) blockoff[t] = tmp[t] - v;
}

__global__ void scan3_kernel(int* __restrict__ row_start, const int* __restrict__ blockoff,
                             int* __restrict__ cursor) {
    int i = blockIdx.x * 256 + threadIdx.x;
    if (i < NNODES) {
        int rs = row_start[i] + blockoff[blockIdx.x];
        row_start[i] = rs;
        cursor[i] = rs;
    }
}

// bijective XCD swizzle (m204)
__device__ __forceinline__ int xcd_swizzle(int bid, int nwg) {
    int xcd = bid & 7;
    int idx = bid >> 3;
    int q = nwg >> 3, r = nwg & 7;
    int base = (xcd < r) ? xcd * (q + 1) : r * (q + 1) + (xcd - r) * q;
    return base + idx;
}

// out[n] = mean over incoming neighbors of bf16 feat[src] (+ fp32 add[n] if ADDV)
// OUTBF: emit bf16 (16B/lane) instead of fp32.
template<int F, bool ADDV, bool OUTBF>
__global__ void gather_mean_bf16_kernel(const int* __restrict__ row_start,
                                        const int* __restrict__ row_end,
                                        const int* __restrict__ csr_src,
                                        const unsigned short* __restrict__ feat,
                                        const float* __restrict__ add,
                                        void* __restrict__ outp, int nwg) {
    constexpr int G = F / 8;        // lanes per node (16 or 8)
    constexpr int NPB = 256 / G;    // nodes per block (16 or 32)
    int blk = xcd_swizzle(blockIdx.x, nwg);
    int node = blk * NPB + threadIdx.x / G;
    int lane = threadIdx.x % G;
    if (node >= NNODES) return;
    int beg = row_start[node];
    int end = row_end[node];
    const uint4* fp = reinterpret_cast<const uint4*>(feat);   // row = G uint4s
    float a[8];
    #pragma unroll
    for (int q = 0; q < 8; ++q) a[q] = 0.f;
    int j = beg;
    for (; j + 3 < end; j += 4) {
        int s0 = csr_src[j];
        int s1 = csr_src[j + 1];
        int s2 = csr_src[j + 2];
        int s3 = csr_src[j + 3];
        uint4 v0 = fp[(size_t)s0 * G + lane];
        uint4 v1 = fp[(size_t)s1 * G + lane];
        uint4 v2 = fp[(size_t)s2 * G + lane];
        uint4 v3 = fp[(size_t)s3 * G + lane];
        acc8(a, v0); acc8(a, v1); acc8(a, v2); acc8(a, v3);
    }
    for (; j < end; ++j) {
        uint4 v0 = fp[(size_t)csr_src[j] * G + lane];
        acc8(a, v0);
    }
    float inv = 1.0f / fmaxf((float)(end - beg), 1.0f);
    #pragma unroll
    for (int q = 0; q < 8; ++q) a[q] *= inv;
    if (OUTBF) {
        uint4 w;
        w.x = (unsigned)f2bf(a[0]) | ((unsigned)f2bf(a[1]) << 16);
        w.y = (unsigned)f2bf(a[2]) | ((unsigned)f2bf(a[3]) << 16);
        w.z = (unsigned)f2bf(a[4]) | ((unsigned)f2bf(a[5]) << 16);
        w.w = (unsigned)f2bf(a[6]) | ((unsigned)f2bf(a[7]) << 16);
        reinterpret_cast<uint4*>(outp)[(size_t)node * G + lane] = w;
    } else {
        float4 o0, o1;
        o0.x = a[0]; o0.y = a[1]; o0.z = a[2]; o0.w = a[3];
        o1.x = a[4]; o1.y = a[5]; o1.z = a[6]; o1.w = a[7];
        if (ADDV) {
            const float4* ap = reinterpret_cast<const float4*>(add + (size_t)node * F + lane * 8);
            float4 r0 = ap[0], r1 = ap[1];
            o0.x += r0.x; o0.y += r0.y; o0.z += r0.z; o0.w += r0.w;
            o1.x += r1.x; o1.y += r1.y; o1.z += r1.z; o1.w += r1.w;
        }
        float4* op = reinterpret_cast<float4*>((float*)outp + (size_t)node * F + lane * 8);
        op[0] = o0; op[1] = o1;
    }
}

// bf16 MFMA GEMM, K=128, N=128, 64 rows/block (4 waves x 16 rows).
// A/B frag: lane holds 8 contiguous k at k = (lane>>4)*8; A row / B col = lane&15.
// C/D: col = lane&15, row = (lane>>4)*4 + reg  [m89 verified].
template<bool LAYER2>
__global__ __launch_bounds__(256) void mfma_gemm_kernel(
    const unsigned short* __restrict__ A1, const unsigned short* __restrict__ A2,
    const unsigned short* __restrict__ Wt1, const unsigned short* __restrict__ Wt2,
    const float* __restrict__ bias,
    unsigned short* __restrict__ outB, float* __restrict__ outF, int M)
{
    const int wave = threadIdx.x >> 6;
    const int lane = threadIdx.x & 63;
    const int rsub = lane & 15;
    const int kgrp = lane >> 4;
    const int koff = kgrp * 8;
    const int row0 = blockIdx.x * 64 + wave * 16;
    const int arow = row0 + rsub;
    const bool avalid = arow < M;

    f32x4 acc[8];
    #pragma unroll
    for (int n = 0; n < 8; ++n) acc[n] = (f32x4){0.f, 0.f, 0.f, 0.f};

    #pragma unroll
    for (int mat = 0; mat < (LAYER2 ? 1 : 2); ++mat) {
        const unsigned short* __restrict__ A = mat ? A2 : A1;
        const unsigned short* __restrict__ W = mat ? Wt2 : Wt1;
        #pragma unroll
        for (int kk = 0; kk < 128; kk += 32) {
            bf16x8 af = {0, 0, 0, 0, 0, 0, 0, 0};
            if (avalid)
                af = *reinterpret_cast<const bf16x8*>(A + (size_t)arow * 128 + kk + koff);
            bf16x8 bfr[8];
            #pragma unroll
            for (int n = 0; n < 8; ++n)
                bfr[n] = *reinterpret_cast<const bf16x8*>(W + (size_t)(n * 16 + rsub) * 128 + kk + koff);
            #pragma unroll
            for (int n = 0; n < 8; ++n)
                acc[n] = __builtin_amdgcn_mfma_f32_16x16x32_bf16(af, bfr[n], acc[n], 0, 0, 0);
        }
    }

    const int orow0 = row0 + kgrp * 4;
    if (!LAYER2) {
        float bv[8];
        #pragma unroll
        for (int n = 0; n < 8; ++n) bv[n] = bias[n * 16 + rsub];
        #pragma unroll
        for (int reg = 0; reg < 4; ++reg) {
            int orow = orow0 + reg;
            if (orow < M) {
                #pragma unroll
                for (int n = 0; n < 8; ++n) {
                    float v = fmaxf(acc[n][reg] + bv[n], 0.f);
                    outB[(size_t)orow * 128 + n * 16 + rsub] = f2bf(v);
                }
            }
        }
    } else {
        float bv[4];
        #pragma unroll
        for (int n = 0; n < 4; ++n) bv[n] = bias[n * 16 + rsub];
        #pragma unroll
        for (int reg = 0; reg < 4; ++reg) {
            int orow = orow0 + reg;
            if (orow < M) {
                #pragma unroll
                for (int n = 0; n < 4; ++n)
                    outB[(size_t)orow * 64 + n * 16 + rsub] = f2bf(acc[n][reg]);
                #pragma unroll
                for (int n = 0; n < 4; ++n)
                    outF[(size_t)orow * 64 + n * 16 + rsub] = acc[n + 4][reg] + bv[n];
            }
        }
    }
}

extern "C" void kernel_launch(void* const* d_in, const int* in_sizes, int n_in,
                              void* d_out, int out_size, void* d_ws, size_t ws_size,
                              hipStream_t stream)
{
    const float* x   = (const float*)d_in[0];
    const int*   ei  = (const int*)d_in[1];
    const float* W1l = (const float*)d_in[2];
    const float* W1r = (const float*)d_in[3];
    const float* b1  = (const float*)d_in[4];
    const float* W2l = (const float*)d_in[5];
    const float* W2r = (const float*)d_in[6];
    const float* b2  = (const float*)d_in[7];
    const int* src = ei;
    const int* dst = ei + NEDGES;

    char* ws = (char*)d_ws;
    int*   deg_i     = (int*)(ws + 0);                    // 400,000 B
    int*   slice_alloc = (int*)(ws + 400000);             // 32 B (zeroed with deg)
    int*   row_start = (int*)(ws + 400128);               // 400,000 B
    int*   cursor    = (int*)(ws + 800256);               // 400,000 B (becomes row_end)
    int*   blocksum  = (int*)(ws + 1200384);
    int*   blockoff  = (int*)(ws + 1202048);
    unsigned short* Wt1l = (unsigned short*)(ws + 1203712);   // 32 KB bf16 [n][k]
    unsigned short* Wt1r = (unsigned short*)(ws + 1236480);   // 32 KB
    unsigned short* Wt2  = (unsigned short*)(ws + 1269248);   // 32 KB ([W2l|W2r] cols)
    int*   csr_src   = (int*)(ws + 1302016);              // 6,400,000 B
    unsigned short* agg1b = (unsigned short*)(ws + 7702016);  // N*128 bf16 (25.6 MB)
    unsigned short* p     = (unsigned short*)(ws + 7702016);  // N*64 bf16 (reuse after gemm1)
    float* r         = (float*)(ws + 20502016);           // N*64 fp32 (25.6 MB)
    // staging aliases r's region (dead until gemm2out writes r, long after B2)
    int*   stagedD   = (int*)(ws + 20502016);             // 8 x 262144 x 4 = 8.39 MB
    int*   stagedS   = (int*)(ws + 28902016);             // 8.39 MB (ends 37.3MB < r end)
    unsigned short* h_bf16 = (unsigned short*)(ws + 46102016);// N*128 bf16 (25.6 MB)
    unsigned short* x_bf16 = (unsigned short*)(ws + 71702016);// N*128 bf16 (25.6 MB)
    float* out       = (float*)d_out;

    // ---- CSR build (two-phase binned) + casts ----
    zero_int_kernel<<<(NNODES + 8 + 255) / 256, 256, 0, stream>>>(deg_i, NNODES + 8);
    binA_kernel<<<256, 256, 0, stream>>>(src, dst, slice_alloc, stagedD, stagedS);
    binB1_kernel<<<2048, 256, 0, stream>>>(slice_alloc, stagedD, deg_i);
    xcast_kernel<<<(NNODES * K / 8 + 255) / 256, 256, 0, stream>>>(
        (const float4*)x, (uint4*)x_bf16, NNODES * K / 8);
    wprep_kernel<<<64, 256, 0, stream>>>(W1l, W1r, W2l, W2r, Wt1l, Wt1r, Wt2);
    scan1_kernel<<<NB1, 256, 0, stream>>>(deg_i, row_start, blocksum);
    scan2_kernel<<<1, 512, 0, stream>>>(blocksum, blockoff);
    scan3_kernel<<<NB1, 256, 0, stream>>>(row_start, blockoff, cursor);
    binB2_kernel<<<2048, 256, 0, stream>>>(slice_alloc, stagedD, stagedS, cursor, csr_src);

    // ---- layer 1: agg1b = mean(x_bf16[nbrs]) (bf16); h = relu(agg1b@W1l + x@W1r + b1) ----
    {
        int nwg = (NNODES + 15) / 16;
        gather_mean_bf16_kernel<128, false, true><<<nwg, 256, 0, stream>>>(
            row_start, cursor, csr_src, x_bf16, nullptr, agg1b, nwg);
    }
    mfma_gemm_kernel<false><<<(NNODES + 63) / 64, 256, 0, stream>>>(
        agg1b, x_bf16, Wt1l, Wt1r, b1, h_bf16, nullptr, NNODES);

    // ---- layer 2: [p|r] = h@[W2l|W2r] (+b2 on r); out = mean(p[nbrs]) + r ----
    mfma_gemm_kernel<true><<<(NNODES + 63) / 64, 256, 0, stream>>>(
        h_bf16, nullptr, Wt2, nullptr, b2, p, r, NNODES);
    {
        int nwg = (NNODES + 31) / 32;
        gather_mean_bf16_kernel<64, true, false><<<nwg, 256, 0, stream>>>(
            row_start, cursor, csr_src, p, r, out, nwg);
    }
}

// Round 8
// 334.202 us; speedup vs baseline: 1.1014x; 1.1014x over previous
//
#include <hip/hip_runtime.h>

constexpr int NNODES = 100000;
constexpr int NEDGES = 1600000;
constexpr int K = 128;
constexpr int NB1 = (NNODES + 255) / 256;   // 391 scan blocks
constexpr int NSLICE = 8;
constexpr int NODES_PER_SLICE = NNODES / NSLICE;   // 12500
constexpr int FILL_BSLOTS = 256;
constexpr int EPB = NEDGES / FILL_BSLOTS;          // 6250 edges per block-slot

typedef __attribute__((ext_vector_type(8))) short bf16x8;
typedef __attribute__((ext_vector_type(4))) float f32x4;

__device__ __forceinline__ unsigned short f2bf(float f) {   // RTNE
    unsigned u = __float_as_uint(f);
    unsigned r = (u + 0x7fffu + ((u >> 16) & 1u)) >> 16;
    return (unsigned short)r;
}
__device__ __forceinline__ void acc2(float& a0, float& a1, unsigned u) {
    a0 += __uint_as_float(u << 16);
    a1 += __uint_as_float(u & 0xffff0000u);
}
__device__ __forceinline__ void acc8(float* a, uint4 v) {
    acc2(a[0], a[1], v.x); acc2(a[2], a[3], v.y);
    acc2(a[4], a[5], v.z); acc2(a[6], a[7], v.w);
}

__global__ void zero_int_kernel(int* __restrict__ p, int n) {
    int i = blockIdx.x * 256 + threadIdx.x;
    if (i < n) p[i] = 0;
}

// x (fp32) -> bf16, 8 elems/thread
__global__ void xcast_kernel(const float4* __restrict__ in, uint4* __restrict__ out, int n8) {
    int i = blockIdx.x * 256 + threadIdx.x;
    if (i >= n8) return;
    float4 a = in[2 * i], b = in[2 * i + 1];
    uint4 w;
    w.x = (unsigned)f2bf(a.x) | ((unsigned)f2bf(a.y) << 16);
    w.y = (unsigned)f2bf(a.z) | ((unsigned)f2bf(a.w) << 16);
    w.z = (unsigned)f2bf(b.x) | ((unsigned)f2bf(b.y) << 16);
    w.w = (unsigned)f2bf(b.z) | ((unsigned)f2bf(b.w) << 16);
    out[i] = w;
}

// cast + transpose weights to bf16 [N][K]; Wt2 = concat([W2l|W2r] cols)
__global__ void wprep_kernel(const float* __restrict__ W1l, const float* __restrict__ W1r,
                             const float* __restrict__ W2l, const float* __restrict__ W2r,
                             unsigned short* __restrict__ Wt1l, unsigned short* __restrict__ Wt1r,
                             unsigned short* __restrict__ Wt2) {
    int idx = blockIdx.x * 256 + threadIdx.x;     // [n][k], n-major
    if (idx >= 128 * 128) return;
    int n = idx >> 7, k = idx & 127;
    Wt1l[idx] = f2bf(W1l[k * 128 + n]);
    Wt1r[idx] = f2bf(W1r[k * 128 + n]);
    Wt2[idx]  = f2bf(n < 64 ? W2l[k * 64 + n] : W2r[k * 64 + (n - 64)]);
}

__global__ void hist_kernel(const int* __restrict__ dst, int* __restrict__ deg) {
    int e = blockIdx.x * 256 + threadIdx.x;
    if (e < NEDGES) atomicAdd(&deg[dst[e]], 1);
}

__global__ void scan1_kernel(const int* __restrict__ deg, int* __restrict__ row_start,
                             int* __restrict__ blocksum) {
    __shared__ int tmp[256];
    int i = blockIdx.x * 256 + threadIdx.x;
    int v = (i < NNODES) ? deg[i] : 0;
    tmp[threadIdx.x] = v;
    __syncthreads();
    #pragma unroll
    for (int off = 1; off < 256; off <<= 1) {
        int t = (threadIdx.x >= off) ? tmp[threadIdx.x - off] : 0;
        __syncthreads();
        tmp[threadIdx.x] += t;
        __syncthreads();
    }
    if (i < NNODES) row_start[i] = tmp[threadIdx.x] - v;   // exclusive
    if (threadIdx.x == 255) blocksum[blockIdx.x] = tmp[255];
}

__global__ void scan2_kernel(int* __restrict__ blocksum, int* __restrict__ blockoff) {
    __shared__ int tmp[512];
    int t = threadIdx.x;
    int v = (t < NB1) ? blocksum[t] : 0;
    tmp[t] = v;
    __syncthreads();
    #pragma unroll
    for (int off = 1; off < 512; off <<= 1) {
        int u = (t >= off) ? tmp[t - off] : 0;
        __syncthreads();
        tmp[t] += u;
        __syncthreads();
    }
    if (t < NB1) blockoff[t] = tmp[t] - v;
}

__global__ void scan3_kernel(int* __restrict__ row_start, const int* __restrict__ blockoff,
                             int* __restrict__ cursor) {
    int i = blockIdx.x * 256 + threadIdx.x;
    if (i < NNODES) {
        int rs = row_start[i] + blockoff[blockIdx.x];
        row_start[i] = rs;
        cursor[i] = rs;
    }
}

// XCD-sliced CSR fill (R3 win)
__global__ void fill_sliced_kernel(const int* __restrict__ src, const int* __restrict__ dst,
                                   int* __restrict__ cursor, int* __restrict__ csr_src) {
    int bslot = blockIdx.x >> 3;
    int slice = blockIdx.x & 7;
    int lo = slice * NODES_PER_SLICE;
    int hi = lo + NODES_PER_SLICE;
    int base = bslot * EPB;
    for (int e = base + threadIdx.x; e < base + EPB; e += 256) {
        int d = dst[e];
        if (d >= lo && d < hi) {
            int pos = atomicAdd(&cursor[d], 1);
            csr_src[pos] = src[e];
        }
    }
}

// bijective XCD swizzle (m204)
__device__ __forceinline__ int xcd_swizzle(int bid, int nwg) {
    int xcd = bid & 7;
    int idx = bid >> 3;
    int q = nwg >> 3, r = nwg & 7;
    int base = (xcd < r) ? xcd * (q + 1) : r * (q + 1) + (xcd - r) * q;
    return base + idx;
}

// out[n] = mean over incoming neighbors of bf16 feat[src] (+ fp32 add[n] if ADDV)
template<int F, bool ADDV, bool OUTBF>
__global__ void gather_mean_bf16_kernel(const int* __restrict__ row_start,
                                        const int* __restrict__ row_end,
                                        const int* __restrict__ csr_src,
                                        const unsigned short* __restrict__ feat,
                                        const float* __restrict__ add,
                                        void* __restrict__ outp, int nwg) {
    constexpr int G = F / 8;        // lanes per node (16 or 8)
    constexpr int NPB = 256 / G;    // nodes per block (16 or 32)
    int blk = xcd_swizzle(blockIdx.x, nwg);
    int node = blk * NPB + threadIdx.x / G;
    int lane = threadIdx.x % G;
    if (node >= NNODES) return;
    int beg = row_start[node];
    int end = row_end[node];
    const uint4* fp = reinterpret_cast<const uint4*>(feat);   // row = G uint4s
    float a[8];
    #pragma unroll
    for (int q = 0; q < 8; ++q) a[q] = 0.f;
    int j = beg;
    for (; j + 3 < end; j += 4) {
        int s0 = csr_src[j];
        int s1 = csr_src[j + 1];
        int s2 = csr_src[j + 2];
        int s3 = csr_src[j + 3];
        uint4 v0 = fp[(size_t)s0 * G + lane];
        uint4 v1 = fp[(size_t)s1 * G + lane];
        uint4 v2 = fp[(size_t)s2 * G + lane];
        uint4 v3 = fp[(size_t)s3 * G + lane];
        acc8(a, v0); acc8(a, v1); acc8(a, v2); acc8(a, v3);
    }
    for (; j < end; ++j) {
        uint4 v0 = fp[(size_t)csr_src[j] * G + lane];
        acc8(a, v0);
    }
    float inv = 1.0f / fmaxf((float)(end - beg), 1.0f);
    #pragma unroll
    for (int q = 0; q < 8; ++q) a[q] *= inv;
    if (OUTBF) {
        uint4 w;
        w.x = (unsigned)f2bf(a[0]) | ((unsigned)f2bf(a[1]) << 16);
        w.y = (unsigned)f2bf(a[2]) | ((unsigned)f2bf(a[3]) << 16);
        w.z = (unsigned)f2bf(a[4]) | ((unsigned)f2bf(a[5]) << 16);
        w.w = (unsigned)f2bf(a[6]) | ((unsigned)f2bf(a[7]) << 16);
        reinterpret_cast<uint4*>(outp)[(size_t)node * G + lane] = w;
    } else {
        float4 o0, o1;
        o0.x = a[0]; o0.y = a[1]; o0.z = a[2]; o0.w = a[3];
        o1.x = a[4]; o1.y = a[5]; o1.z = a[6]; o1.w = a[7];
        if (ADDV) {
            const float4* ap = reinterpret_cast<const float4*>(add + (size_t)node * F + lane * 8);
            float4 r0 = ap[0], r1 = ap[1];
            o0.x += r0.x; o0.y += r0.y; o0.z += r0.z; o0.w += r0.w;
            o1.x += r1.x; o1.y += r1.y; o1.z += r1.z; o1.w += r1.w;
        }
        float4* op = reinterpret_cast<float4*>((float*)outp + (size_t)node * F + lane * 8);
        op[0] = o0; op[1] = o1;
    }
}

// bf16 MFMA GEMM, K=128, N=128, 128 rows/block (4 waves x two 16-row tiles).
// SWAPPED operands: acc = mfma(w_frag, node_frag) -> D[i=wcol][j=node row]
// lane holds out[row0+rsub][n*16 + kgrp*4 + reg], reg=0..3 -> 4 consecutive cols
// => packed uint2 (bf16x4) / float4 stores. Derived from the R5 empirically-
// verified mapping by transposition.
template<bool LAYER2>
__global__ __launch_bounds__(256) void mfma_gemm_kernel(
    const unsigned short* __restrict__ A1, const unsigned short* __restrict__ A2,
    const unsigned short* __restrict__ Wt1, const unsigned short* __restrict__ Wt2,
    const float* __restrict__ bias,
    unsigned short* __restrict__ outB, float* __restrict__ outF, int M)
{
    const int wave = threadIdx.x >> 6;
    const int lane = threadIdx.x & 63;
    const int rsub = lane & 15;
    const int kgrp = lane >> 4;
    const int koff = kgrp * 8;
    const int row0 = blockIdx.x * 128 + wave * 32;   // two tiles: row0, row0+16
    const int ar0 = row0 + rsub;
    const int ar1 = row0 + 16 + rsub;
    const bool v0 = ar0 < M, v1 = ar1 < M;

    f32x4 acc[2][8];
    #pragma unroll
    for (int t = 0; t < 2; ++t)
        #pragma unroll
        for (int n = 0; n < 8; ++n) acc[t][n] = (f32x4){0.f, 0.f, 0.f, 0.f};

    #pragma unroll
    for (int mat = 0; mat < (LAYER2 ? 1 : 2); ++mat) {
        const unsigned short* __restrict__ A = mat ? A2 : A1;
        const unsigned short* __restrict__ W = mat ? Wt2 : Wt1;
        #pragma unroll
        for (int kk = 0; kk < 128; kk += 32) {
            bf16x8 a0 = {0, 0, 0, 0, 0, 0, 0, 0};
            bf16x8 a1 = {0, 0, 0, 0, 0, 0, 0, 0};
            if (v0) a0 = *reinterpret_cast<const bf16x8*>(A + (size_t)ar0 * 128 + kk + koff);
            if (v1) a1 = *reinterpret_cast<const bf16x8*>(A + (size_t)ar1 * 128 + kk + koff);
            #pragma unroll
            for (int n = 0; n < 8; ++n) {
                bf16x8 w = *reinterpret_cast<const bf16x8*>(W + (size_t)(n * 16 + rsub) * 128 + kk + koff);
                acc[0][n] = __builtin_amdgcn_mfma_f32_16x16x32_bf16(w, a0, acc[0][n], 0, 0, 0);
                acc[1][n] = __builtin_amdgcn_mfma_f32_16x16x32_bf16(w, a1, acc[1][n], 0, 0, 0);
            }
        }
    }

    if (!LAYER2) {
        float4 bv[8];
        #pragma unroll
        for (int n = 0; n < 8; ++n)
            bv[n] = *reinterpret_cast<const float4*>(bias + n * 16 + kgrp * 4);
        #pragma unroll
        for (int t = 0; t < 2; ++t) {
            int ar = t ? ar1 : ar0;
            if (!(t ? v1 : v0)) continue;
            #pragma unroll
            for (int n = 0; n < 8; ++n) {
                float e0 = fmaxf(acc[t][n][0] + bv[n].x, 0.f);
                float e1 = fmaxf(acc[t][n][1] + bv[n].y, 0.f);
                float e2 = fmaxf(acc[t][n][2] + bv[n].z, 0.f);
                float e3 = fmaxf(acc[t][n][3] + bv[n].w, 0.f);
                uint2 pw;
                pw.x = (unsigned)f2bf(e0) | ((unsigned)f2bf(e1) << 16);
                pw.y = (unsigned)f2bf(e2) | ((unsigned)f2bf(e3) << 16);
                *reinterpret_cast<uint2*>(outB + (size_t)ar * 128 + n * 16 + kgrp * 4) = pw;
            }
        }
    } else {
        float4 bv[4];
        #pragma unroll
        for (int n = 0; n < 4; ++n)
            bv[n] = *reinterpret_cast<const float4*>(bias + n * 16 + kgrp * 4);
        #pragma unroll
        for (int t = 0; t < 2; ++t) {
            int ar = t ? ar1 : ar0;
            if (!(t ? v1 : v0)) continue;
            #pragma unroll
            for (int n = 0; n < 4; ++n) {      // cols 0-63 -> p (bf16)
                uint2 pw;
                pw.x = (unsigned)f2bf(acc[t][n][0]) | ((unsigned)f2bf(acc[t][n][1]) << 16);
                pw.y = (unsigned)f2bf(acc[t][n][2]) | ((unsigned)f2bf(acc[t][n][3]) << 16);
                *reinterpret_cast<uint2*>(outB + (size_t)ar * 64 + n * 16 + kgrp * 4) = pw;
            }
            #pragma unroll
            for (int n = 0; n < 4; ++n) {      // cols 64-127 -> r (fp32, +b2)
                float4 o;
                o.x = acc[t][n + 4][0] + bv[n].x;
                o.y = acc[t][n + 4][1] + bv[n].y;
                o.z = acc[t][n + 4][2] + bv[n].z;
                o.w = acc[t][n + 4][3] + bv[n].w;
                *reinterpret_cast<float4*>(outF + (size_t)ar * 64 + n * 16 + kgrp * 4) = o;
            }
        }
    }
}

extern "C" void kernel_launch(void* const* d_in, const int* in_sizes, int n_in,
                              void* d_out, int out_size, void* d_ws, size_t ws_size,
                              hipStream_t stream)
{
    const float* x   = (const float*)d_in[0];
    const int*   ei  = (const int*)d_in[1];
    const float* W1l = (const float*)d_in[2];
    const float* W1r = (const float*)d_in[3];
    const float* b1  = (const float*)d_in[4];
    const float* W2l = (const float*)d_in[5];
    const float* W2r = (const float*)d_in[6];
    const float* b2  = (const float*)d_in[7];
    const int* src = ei;
    const int* dst = ei + NEDGES;

    char* ws = (char*)d_ws;
    int*   deg_i     = (int*)(ws + 0);                    // 400,000 B
    int*   row_start = (int*)(ws + 400128);               // 400,000 B
    int*   cursor    = (int*)(ws + 800256);               // 400,000 B (becomes row_end)
    int*   blocksum  = (int*)(ws + 1200384);
    int*   blockoff  = (int*)(ws + 1202048);
    unsigned short* Wt1l = (unsigned short*)(ws + 1203712);   // 32 KB bf16 [n][k]
    unsigned short* Wt1r = (unsigned short*)(ws + 1236480);   // 32 KB
    unsigned short* Wt2  = (unsigned short*)(ws + 1269248);   // 32 KB ([W2l|W2r] cols)
    int*   csr_src   = (int*)(ws + 1302016);              // 6,400,000 B
    unsigned short* agg1b = (unsigned short*)(ws + 7702016);  // N*128 bf16 (25.6 MB)
    unsigned short* p     = (unsigned short*)(ws + 7702016);  // N*64 bf16 (reuse after gemm1)
    float* r         = (float*)(ws + 20502016);           // N*64 fp32 (25.6 MB)
    unsigned short* h_bf16 = (unsigned short*)(ws + 46102016);// N*128 bf16 (25.6 MB)
    unsigned short* x_bf16 = (unsigned short*)(ws + 71702016);// N*128 bf16 (25.6 MB)
    float* out       = (float*)d_out;

    // ---- CSR build (R5 structure) + casts ----
    zero_int_kernel<<<(NNODES + 255) / 256, 256, 0, stream>>>(deg_i, NNODES);
    hist_kernel<<<(NEDGES + 255) / 256, 256, 0, stream>>>(dst, deg_i);
    xcast_kernel<<<(NNODES * K / 8 + 255) / 256, 256, 0, stream>>>(
        (const float4*)x, (uint4*)x_bf16, NNODES * K / 8);
    wprep_kernel<<<64, 256, 0, stream>>>(W1l, W1r, W2l, W2r, Wt1l, Wt1r, Wt2);
    scan1_kernel<<<NB1, 256, 0, stream>>>(deg_i, row_start, blocksum);
    scan2_kernel<<<1, 512, 0, stream>>>(blocksum, blockoff);
    scan3_kernel<<<NB1, 256, 0, stream>>>(row_start, blockoff, cursor);
    fill_sliced_kernel<<<FILL_BSLOTS * NSLICE, 256, 0, stream>>>(src, dst, cursor, csr_src);

    // ---- layer 1 ----
    {
        int nwg = (NNODES + 15) / 16;
        gather_mean_bf16_kernel<128, false, true><<<nwg, 256, 0, stream>>>(
            row_start, cursor, csr_src, x_bf16, nullptr, agg1b, nwg);
    }
    mfma_gemm_kernel<false><<<(NNODES + 127) / 128, 256, 0, stream>>>(
        agg1b, x_bf16, Wt1l, Wt1r, b1, h_bf16, nullptr, NNODES);

    // ---- layer 2: [p|r] = h@[W2l|W2r] (+b2 on r); out = mean(p[nbrs]) + r ----
    mfma_gemm_kernel<true><<<(NNODES + 127) / 128, 256, 0, stream>>>(
        h_bf16, nullptr, Wt2, nullptr, b2, p, r, NNODES);
    {
        int nwg = (NNODES + 31) / 32;
        gather_mean_bf16_kernel<64, true, false><<<nwg, 256, 0, stream>>>(
            row_start, cursor, csr_src, p, r, out, nwg);
    }
}

// Round 9
// 230.840 us; speedup vs baseline: 1.5946x; 1.4478x over previous
//
#include <hip/hip_runtime.h>

constexpr int NNODES = 100000;
constexpr int NEDGES = 1600000;
constexpr int K = 128;
constexpr int NBUCKET = 391;              // ceil(100000/256), bucket = dst>>8
constexpr int BCAP = 6144;                // expected 4096, +32 sigma
constexpr int A_EPB = NEDGES / 256;       // 6250 edges per binA block

typedef __attribute__((ext_vector_type(8))) short bf16x8;
typedef __attribute__((ext_vector_type(4))) float f32x4;

__device__ __forceinline__ unsigned short f2bf(float f) {   // RTNE
    unsigned u = __float_as_uint(f);
    unsigned r = (u + 0x7fffu + ((u >> 16) & 1u)) >> 16;
    return (unsigned short)r;
}
__device__ __forceinline__ void acc2(float& a0, float& a1, unsigned u) {
    a0 += __uint_as_float(u << 16);
    a1 += __uint_as_float(u & 0xffff0000u);
}
__device__ __forceinline__ void acc8(float* a, uint4 v) {
    acc2(a[0], a[1], v.x); acc2(a[2], a[3], v.y);
    acc2(a[4], a[5], v.z); acc2(a[6], a[7], v.w);
}

__global__ void zero_int_kernel(int* __restrict__ p, int n) {
    int i = blockIdx.x * 256 + threadIdx.x;
    if (i < n) p[i] = 0;
}

// x (fp32) -> bf16, 8 elems/thread
__global__ void xcast_kernel(const float4* __restrict__ in, uint4* __restrict__ out, int n8) {
    int i = blockIdx.x * 256 + threadIdx.x;
    if (i >= n8) return;
    float4 a = in[2 * i], b = in[2 * i + 1];
    uint4 w;
    w.x = (unsigned)f2bf(a.x) | ((unsigned)f2bf(a.y) << 16);
    w.y = (unsigned)f2bf(a.z) | ((unsigned)f2bf(a.w) << 16);
    w.z = (unsigned)f2bf(b.x) | ((unsigned)f2bf(b.y) << 16);
    w.w = (unsigned)f2bf(b.z) | ((unsigned)f2bf(b.w) << 16);
    out[i] = w;
}

// cast + transpose weights to bf16 [N][K]; Wt2 = concat([W2l|W2r] cols)
__global__ void wprep_kernel(const float* __restrict__ W1l, const float* __restrict__ W1r,
                             const float* __restrict__ W2l, const float* __restrict__ W2r,
                             unsigned short* __restrict__ Wt1l, unsigned short* __restrict__ Wt1r,
                             unsigned short* __restrict__ Wt2) {
    int idx = blockIdx.x * 256 + threadIdx.x;     // [n][k], n-major
    if (idx >= 128 * 128) return;
    int n = idx >> 7, k = idx & 127;
    Wt1l[idx] = f2bf(W1l[k * 128 + n]);
    Wt1r[idx] = f2bf(W1r[k * 128 + n]);
    Wt2[idx]  = f2bf(n < 64 ? W2l[k * 64 + n] : W2r[k * 64 + (n - 64)]);
}

// Pass A: block loads 6250 edges, LDS counting-sort by bucket (dst>>8),
// then writes each bucket's records as a CONTIGUOUS run into that bucket's
// global region (one atomicAdd per block x bucket). Kills scattered stores.
__global__ __launch_bounds__(256) void binA_kernel(
    const int* __restrict__ src, const int* __restrict__ dst,
    int* __restrict__ bucket_alloc, int2* __restrict__ regions)
{
    __shared__ int hist[NBUCKET];
    __shared__ int lstart[NBUCKET];
    __shared__ int gbase[NBUCKET];
    __shared__ int cur[NBUCKET];
    __shared__ int sD[A_EPB];
    __shared__ int sS[A_EPB];
    __shared__ int oD[A_EPB];
    __shared__ int oS[A_EPB];
    const int tid = threadIdx.x;
    for (int i = tid; i < NBUCKET; i += 256) hist[i] = 0;
    __syncthreads();
    const int e0 = blockIdx.x * A_EPB;
    for (int i = tid; i < A_EPB; i += 256) {
        int d = dst[e0 + i];
        sD[i] = d; sS[i] = src[e0 + i];
        atomicAdd(&hist[d >> 8], 1);
    }
    __syncthreads();
    if (tid == 0) {                     // serial scan, ~391 iters, concurrent across blocks
        int acc = 0;
        for (int b = 0; b < NBUCKET; ++b) { lstart[b] = acc; acc += hist[b]; }
    }
    __syncthreads();
    for (int b = tid; b < NBUCKET; b += 256) {
        gbase[b] = atomicAdd(&bucket_alloc[b], hist[b]);
        cur[b] = lstart[b];
    }
    __syncthreads();
    for (int i = tid; i < A_EPB; i += 256) {
        int d = sD[i];
        int p = atomicAdd(&cur[d >> 8], 1);
        oD[p] = d; oS[p] = sS[i];
    }
    __syncthreads();
    for (int j = tid; j < A_EPB; j += 256) {
        int d = oD[j];
        int b = d >> 8;
        int pos = gbase[b] + (j - lstart[b]);
        if (pos < BCAP)                 // >32-sigma guard
            regions[(size_t)b * BCAP + pos] = make_int2(d, oS[j]);
    }
}

// exclusive scan of 391 bucket totals -> bucket_base (csr offset of each bucket)
__global__ void scanB_kernel(const int* __restrict__ bucket_alloc, int* __restrict__ bucket_base) {
    __shared__ int tmp[512];
    int t = threadIdx.x;
    int v = (t < NBUCKET) ? min(bucket_alloc[t], BCAP) : 0;
    tmp[t] = v;
    __syncthreads();
    #pragma unroll
    for (int off = 1; off < 512; off <<= 1) {
        int u = (t >= off) ? tmp[t - off] : 0;
        __syncthreads();
        tmp[t] += u;
        __syncthreads();
    }
    if (t < NBUCKET) bucket_base[t] = tmp[t] - v;
}

// Pass B: one block per bucket. Read contiguous records, LDS counting-sort by
// node, write csr_src fully COALESCED + emit row_start/row_end for the
// bucket's 256 nodes (replaces hist + scan1/2/3 + fill).
__global__ __launch_bounds__(256) void binB_kernel(
    const int2* __restrict__ regions, const int* __restrict__ bucket_alloc,
    const int* __restrict__ bucket_base,
    int* __restrict__ row_start, int* __restrict__ row_end, int* __restrict__ csr_src)
{
    __shared__ int hist[256];
    __shared__ int loff[256];
    __shared__ int cur[256];
    __shared__ int sD[BCAP];
    __shared__ int sS[BCAP];
    __shared__ int sorted[BCAP];
    const int b = blockIdx.x;
    const int tid = threadIdx.x;
    const int n = min(bucket_alloc[b], BCAP);
    const int base = bucket_base[b];
    hist[tid] = 0;
    __syncthreads();
    for (int i = tid; i < n; i += 256) {
        int2 rec = regions[(size_t)b * BCAP + i];
        sD[i] = rec.x; sS[i] = rec.y;
        atomicAdd(&hist[rec.x & 255], 1);
    }
    __syncthreads();
    int v = hist[tid];
    loff[tid] = v;
    __syncthreads();
    #pragma unroll
    for (int off = 1; off < 256; off <<= 1) {
        int u = (tid >= off) ? loff[tid - off] : 0;
        __syncthreads();
        loff[tid] += u;
        __syncthreads();
    }
    int excl = loff[tid] - v;
    cur[tid] = excl;
    int node = b * 256 + tid;
    if (node < NNODES) {
        row_start[node] = base + excl;
        row_end[node] = base + excl + v;
    }
    __syncthreads();
    for (int i = tid; i < n; i += 256) {
        int p = atomicAdd(&cur[sD[i] & 255], 1);
        sorted[p] = sS[i];
    }
    __syncthreads();
    for (int j = tid; j < n; j += 256)
        csr_src[base + j] = sorted[j];
}

// bijective XCD swizzle (m204)
__device__ __forceinline__ int xcd_swizzle(int bid, int nwg) {
    int xcd = bid & 7;
    int idx = bid >> 3;
    int q = nwg >> 3, r = nwg & 7;
    int base = (xcd < r) ? xcd * (q + 1) : r * (q + 1) + (xcd - r) * q;
    return base + idx;
}

// out[n] = mean over incoming neighbors of bf16 feat[src] (+ fp32 add[n] if ADDV)
template<int F, bool ADDV, bool OUTBF>
__global__ void gather_mean_bf16_kernel(const int* __restrict__ row_start,
                                        const int* __restrict__ row_end,
                                        const int* __restrict__ csr_src,
                                        const unsigned short* __restrict__ feat,
                                        const float* __restrict__ add,
                                        void* __restrict__ outp, int nwg) {
    constexpr int G = F / 8;        // lanes per node (16 or 8)
    constexpr int NPB = 256 / G;    // nodes per block (16 or 32)
    int blk = xcd_swizzle(blockIdx.x, nwg);
    int node = blk * NPB + threadIdx.x / G;
    int lane = threadIdx.x % G;
    if (node >= NNODES) return;
    int beg = row_start[node];
    int end = row_end[node];
    const uint4* fp = reinterpret_cast<const uint4*>(feat);   // row = G uint4s
    float a[8];
    #pragma unroll
    for (int q = 0; q < 8; ++q) a[q] = 0.f;
    int j = beg;
    for (; j + 3 < end; j += 4) {
        int s0 = csr_src[j];
        int s1 = csr_src[j + 1];
        int s2 = csr_src[j + 2];
        int s3 = csr_src[j + 3];
        uint4 v0 = fp[(size_t)s0 * G + lane];
        uint4 v1 = fp[(size_t)s1 * G + lane];
        uint4 v2 = fp[(size_t)s2 * G + lane];
        uint4 v3 = fp[(size_t)s3 * G + lane];
        acc8(a, v0); acc8(a, v1); acc8(a, v2); acc8(a, v3);
    }
    for (; j < end; ++j) {
        uint4 v0 = fp[(size_t)csr_src[j] * G + lane];
        acc8(a, v0);
    }
    float inv = 1.0f / fmaxf((float)(end - beg), 1.0f);
    #pragma unroll
    for (int q = 0; q < 8; ++q) a[q] *= inv;
    if (OUTBF) {
        uint4 w;
        w.x = (unsigned)f2bf(a[0]) | ((unsigned)f2bf(a[1]) << 16);
        w.y = (unsigned)f2bf(a[2]) | ((unsigned)f2bf(a[3]) << 16);
        w.z = (unsigned)f2bf(a[4]) | ((unsigned)f2bf(a[5]) << 16);
        w.w = (unsigned)f2bf(a[6]) | ((unsigned)f2bf(a[7]) << 16);
        reinterpret_cast<uint4*>(outp)[(size_t)node * G + lane] = w;
    } else {
        float4 o0, o1;
        o0.x = a[0]; o0.y = a[1]; o0.z = a[2]; o0.w = a[3];
        o1.x = a[4]; o1.y = a[5]; o1.z = a[6]; o1.w = a[7];
        if (ADDV) {
            const float4* ap = reinterpret_cast<const float4*>(add + (size_t)node * F + lane * 8);
            float4 r0 = ap[0], r1 = ap[1];
            o0.x += r0.x; o0.y += r0.y; o0.z += r0.z; o0.w += r0.w;
            o1.x += r1.x; o1.y += r1.y; o1.z += r1.z; o1.w += r1.w;
        }
        float4* op = reinterpret_cast<float4*>((float*)outp + (size_t)node * F + lane * 8);
        op[0] = o0; op[1] = o1;
    }
}

// bf16 MFMA GEMM, K=128, N=128, 128 rows/block (4 waves x two 16-row tiles).
// SWAPPED operands (R7 win): lane holds 4 consecutive output cols -> packed stores.
template<bool LAYER2>
__global__ __launch_bounds__(256) void mfma_gemm_kernel(
    const unsigned short* __restrict__ A1, const unsigned short* __restrict__ A2,
    const unsigned short* __restrict__ Wt1, const unsigned short* __restrict__ Wt2,
    const float* __restrict__ bias,
    unsigned short* __restrict__ outB, float* __restrict__ outF, int M)
{
    const int wave = threadIdx.x >> 6;
    const int lane = threadIdx.x & 63;
    const int rsub = lane & 15;
    const int kgrp = lane >> 4;
    const int koff = kgrp * 8;
    const int row0 = blockIdx.x * 128 + wave * 32;   // two tiles: row0, row0+16
    const int ar0 = row0 + rsub;
    const int ar1 = row0 + 16 + rsub;
    const bool v0 = ar0 < M, v1 = ar1 < M;

    f32x4 acc[2][8];
    #pragma unroll
    for (int t = 0; t < 2; ++t)
        #pragma unroll
        for (int n = 0; n < 8; ++n) acc[t][n] = (f32x4){0.f, 0.f, 0.f, 0.f};

    #pragma unroll
    for (int mat = 0; mat < (LAYER2 ? 1 : 2); ++mat) {
        const unsigned short* __restrict__ A = mat ? A2 : A1;
        const unsigned short* __restrict__ W = mat ? Wt2 : Wt1;
        #pragma unroll
        for (int kk = 0; kk < 128; kk += 32) {
            bf16x8 a0 = {0, 0, 0, 0, 0, 0, 0, 0};
            bf16x8 a1 = {0, 0, 0, 0, 0, 0, 0, 0};
            if (v0) a0 = *reinterpret_cast<const bf16x8*>(A + (size_t)ar0 * 128 + kk + koff);
            if (v1) a1 = *reinterpret_cast<const bf16x8*>(A + (size_t)ar1 * 128 + kk + koff);
            #pragma unroll
            for (int n = 0; n < 8; ++n) {
                bf16x8 w = *reinterpret_cast<const bf16x8*>(W + (size_t)(n * 16 + rsub) * 128 + kk + koff);
                acc[0][n] = __builtin_amdgcn_mfma_f32_16x16x32_bf16(w, a0, acc[0][n], 0, 0, 0);
                acc[1][n] = __builtin_amdgcn_mfma_f32_16x16x32_bf16(w, a1, acc[1][n], 0, 0, 0);
            }
        }
    }

    if (!LAYER2) {
        float4 bv[8];
        #pragma unroll
        for (int n = 0; n < 8; ++n)
            bv[n] = *reinterpret_cast<const float4*>(bias + n * 16 + kgrp * 4);
        #pragma unroll
        for (int t = 0; t < 2; ++t) {
            int ar = t ? ar1 : ar0;
            if (!(t ? v1 : v0)) continue;
            #pragma unroll
            for (int n = 0; n < 8; ++n) {
                float e0 = fmaxf(acc[t][n][0] + bv[n].x, 0.f);
                float e1 = fmaxf(acc[t][n][1] + bv[n].y, 0.f);
                float e2 = fmaxf(acc[t][n][2] + bv[n].z, 0.f);
                float e3 = fmaxf(acc[t][n][3] + bv[n].w, 0.f);
                uint2 pw;
                pw.x = (unsigned)f2bf(e0) | ((unsigned)f2bf(e1) << 16);
                pw.y = (unsigned)f2bf(e2) | ((unsigned)f2bf(e3) << 16);
                *reinterpret_cast<uint2*>(outB + (size_t)ar * 128 + n * 16 + kgrp * 4) = pw;
            }
        }
    } else {
        float4 bv[4];
        #pragma unroll
        for (int n = 0; n < 4; ++n)
            bv[n] = *reinterpret_cast<const float4*>(bias + n * 16 + kgrp * 4);
        #pragma unroll
        for (int t = 0; t < 2; ++t) {
            int ar = t ? ar1 : ar0;
            if (!(t ? v1 : v0)) continue;
            #pragma unroll
            for (int n = 0; n < 4; ++n) {      // cols 0-63 -> p (bf16)
                uint2 pw;
                pw.x = (unsigned)f2bf(acc[t][n][0]) | ((unsigned)f2bf(acc[t][n][1]) << 16);
                pw.y = (unsigned)f2bf(acc[t][n][2]) | ((unsigned)f2bf(acc[t][n][3]) << 16);
                *reinterpret_cast<uint2*>(outB + (size_t)ar * 64 + n * 16 + kgrp * 4) = pw;
            }
            #pragma unroll
            for (int n = 0; n < 4; ++n) {      // cols 64-127 -> r (fp32, +b2)
                float4 o;
                o.x = acc[t][n + 4][0] + bv[n].x;
                o.y = acc[t][n + 4][1] + bv[n].y;
                o.z = acc[t][n + 4][2] + bv[n].z;
                o.w = acc[t][n + 4][3] + bv[n].w;
                *reinterpret_cast<float4*>(outF + (size_t)ar * 64 + n * 16 + kgrp * 4) = o;
            }
        }
    }
}

extern "C" void kernel_launch(void* const* d_in, const int* in_sizes, int n_in,
                              void* d_out, int out_size, void* d_ws, size_t ws_size,
                              hipStream_t stream)
{
    const float* x   = (const float*)d_in[0];
    const int*   ei  = (const int*)d_in[1];
    const float* W1l = (const float*)d_in[2];
    const float* W1r = (const float*)d_in[3];
    const float* b1  = (const float*)d_in[4];
    const float* W2l = (const float*)d_in[5];
    const float* W2r = (const float*)d_in[6];
    const float* b2  = (const float*)d_in[7];
    const int* src = ei;
    const int* dst = ei + NEDGES;

    char* ws = (char*)d_ws;
    int*   bucket_alloc = (int*)(ws + 0);                 // 391 ints
    int*   bucket_base  = (int*)(ws + 1664);              // 391 ints
    int*   row_start = (int*)(ws + 400128);               // 400,000 B
    int*   row_end   = (int*)(ws + 800256);               // 400,000 B
    unsigned short* Wt1l = (unsigned short*)(ws + 1203712);   // 32 KB bf16 [n][k]
    unsigned short* Wt1r = (unsigned short*)(ws + 1236480);   // 32 KB
    unsigned short* Wt2  = (unsigned short*)(ws + 1269248);   // 32 KB ([W2l|W2r] cols)
    int*   csr_src   = (int*)(ws + 1302016);              // 6,400,000 B
    unsigned short* agg1b = (unsigned short*)(ws + 7702016);  // N*128 bf16 (25.6 MB)
    unsigned short* p     = (unsigned short*)(ws + 7702016);  // N*64 bf16 (reuse after gemm1)
    float* r         = (float*)(ws + 20502016);           // N*64 fp32 (25.6 MB)
    // regions aliases r (dead until gemm2out writes r, long after binB)
    int2*  regions   = (int2*)(ws + 20502016);            // 391*6144*8 = 19.2 MB
    unsigned short* h_bf16 = (unsigned short*)(ws + 46102016);// N*128 bf16 (25.6 MB)
    unsigned short* x_bf16 = (unsigned short*)(ws + 71702016);// N*128 bf16 (25.6 MB)
    float* out       = (float*)d_out;

    // ---- CSR build: two-pass LDS-bucketed counting sort ----
    zero_int_kernel<<<2, 256, 0, stream>>>(bucket_alloc, NBUCKET);
    binA_kernel<<<256, 256, 0, stream>>>(src, dst, bucket_alloc, regions);
    xcast_kernel<<<(NNODES * K / 8 + 255) / 256, 256, 0, stream>>>(
        (const float4*)x, (uint4*)x_bf16, NNODES * K / 8);
    wprep_kernel<<<64, 256, 0, stream>>>(W1l, W1r, W2l, W2r, Wt1l, Wt1r, Wt2);
    scanB_kernel<<<1, 512, 0, stream>>>(bucket_alloc, bucket_base);
    binB_kernel<<<NBUCKET, 256, 0, stream>>>(regions, bucket_alloc, bucket_base,
                                             row_start, row_end, csr_src);

    // ---- layer 1 ----
    {
        int nwg = (NNODES + 15) / 16;
        gather_mean_bf16_kernel<128, false, true><<<nwg, 256, 0, stream>>>(
            row_start, row_end, csr_src, x_bf16, nullptr, agg1b, nwg);
    }
    mfma_gemm_kernel<false><<<(NNODES + 127) / 128, 256, 0, stream>>>(
        agg1b, x_bf16, Wt1l, Wt1r, b1, h_bf16, nullptr, NNODES);

    // ---- layer 2: [p|r] = h@[W2l|W2r] (+b2 on r); out = mean(p[nbrs]) + r ----
    mfma_gemm_kernel<true><<<(NNODES + 127) / 128, 256, 0, stream>>>(
        h_bf16, nullptr, Wt2, nullptr, b2, p, r, NNODES);
    {
        int nwg = (NNODES + 31) / 32;
        gather_mean_bf16_kernel<64, true, false><<<nwg, 256, 0, stream>>>(
            row_start, row_end, csr_src, p, r, out, nwg);
    }
}